// Round 9
// baseline (31.450 us; speedup 1.0000x reference)
//
#include <hip/hip_runtime.h>

// Helmholtz loss, fully reduced:
//   patch(b,h,w) = w^T H w, w from per-pixel linear fields,
//   H = M^T (a1*C1 + a2*C2 + a3*C3sym) M  (host, double precision).
// Round-9: half-width wave strips (4 patch rows x 256 cols) -> 4096 waves,
// 1024 blocks, launch_bounds(256,4) => 16 waves/CU (2x r8 TLP). Seam at
// col 255/256 via wave-uniform broadcast load of col 256 (no divergence).
// Single kernel: block partial -> ONE fire-and-forget relaxed fp32
// atomicAdd into out[0] (pre-zeroed by 4-byte memset). No ACQ_REL, no
// counter, no second launch (r3-r7 pathology was the acq_rel fence;
// plain atomicAdd is device-scope & cheap). r8-style unrolled pipeline
// with 1-row register lookahead; no LDS / no barriers in hot loop.

struct HParams {
    float u0, u1, u2, u3;
    float H00, H11, H22, H33;
    float H01_2, H02_2, H03_2, H12_2, H13_2, H23_2;
};

#define BSIZE 256
#define NBLK  1024

__device__ __forceinline__ float f4get(const float4& v, int k) {
    switch (k & 3) { case 0: return v.x; case 1: return v.y; case 2: return v.z; default: return v.w; }
}

// Load one data row (this wave's 256-col half): 4 ch x 1 float4 per lane,
// plus (half-0 waves only) the col-256 seam scalar per channel, same
// address across all lanes -> single broadcast request.
#define LOADROW(B, E, r) do {                                                   \
    _Pragma("unroll")                                                           \
    for (int ch = 0; ch < 4; ++ch)                                              \
        B[ch] = px[(size_t)ch * 65536u + (size_t)(r) * 128u + (size_t)cq];      \
    if (seam) {                                                                 \
        _Pragma("unroll")                                                       \
        for (int ch = 0; ch < 4; ++ch)                                          \
            E[ch] = pxf[(size_t)ch * 262144u + (size_t)(r) * 512u + 256u];      \
    } } while (0)

// Adopt row in B/E as the "top" row: T1/T2/T4 per col, Tb2/Tb4 at col 256.
#define TOPF(B, E) do {                                                         \
    _Pragma("unroll")                                                           \
    for (int j = 0; j < 4; ++j) {                                               \
        const float x0_ = f4get(B[0], j), x1_ = f4get(B[1], j);                 \
        const float x2_ = f4get(B[2], j), x3_ = f4get(B[3], j);                 \
        const float t0_ = P.u0 * x0_;                                           \
        T1[j] = fmaf(P.u2, x3_, t0_);                                           \
        T2[j] = fmaf(P.u2, x1_, t0_);                                           \
        T4[j] = fmaf(P.u2, x3_, P.u0 * x2_);                                    \
    }                                                                           \
    Tb2 = fmaf(P.u2, E[1], P.u0 * E[0]);                                        \
    Tb4 = fmaf(P.u2, E[3], P.u0 * E[2]);                                        \
} while (0)

// Row in B/E acts as bottom row of patch row `pr`; accumulate, then adopt
// its top-role fields. `valid` is the wave-uniform patch-row validity.
#define ROWSTEP(B, E, valid) do {                                               \
    float f3_[4], f5_[4];                                                       \
    _Pragma("unroll")                                                           \
    for (int j = 0; j < 4; ++j) {                                               \
        const float x0_ = f4get(B[0], j), x1_ = f4get(B[1], j);                 \
        const float x2_ = f4get(B[2], j), x3_ = f4get(B[3], j);                 \
        f3_[j] = fmaf(P.u3, x1_, P.u1 * x0_);                                   \
        f5_[j] = fmaf(P.u3, x3_, P.u1 * x2_);                                   \
    }                                                                           \
    const float Bb3_ = fmaf(P.u3, E[1], P.u1 * E[0]);                           \
    const float Bb5_ = fmaf(P.u3, E[3], P.u1 * E[2]);                           \
    float aV[4], bV[4], cV[4];                                                  \
    _Pragma("unroll")                                                           \
    for (int j = 0; j < 4; ++j) {                                               \
        aV[j] = T1[j] + f3_[j];                                                 \
        bV[j] = T2[j] + f3_[j];                                                 \
        cV[j] = T4[j] + f5_[j];                                                 \
    }                                                                           \
    float bn_ = __shfl_down(bV[0], 1, 64);                                      \
    float cn_ = __shfl_down(cV[0], 1, 64);                                      \
    if (seam && lane == 63) { bn_ = Tb2 + Bb3_; cn_ = Tb4 + Bb5_; }             \
    float rowsum_ = 0.0f;                                                       \
    _Pragma("unroll")                                                           \
    for (int j = 0; j < 4; ++j) {                                               \
        const float w0_ = aV[j];                                                \
        const float w1_ = (j < 3) ? bV[j + 1] : bn_;                            \
        const float w2_ = cV[j];                                                \
        const float w3_ = (j < 3) ? cV[j + 1] : cn_;                            \
        const float q0_ = fmaf(P.H03_2, w3_, fmaf(P.H02_2, w2_, fmaf(P.H01_2, w1_, P.H00 * w0_))); \
        const float q1_ = fmaf(P.H13_2, w3_, fmaf(P.H12_2, w2_, P.H11 * w1_));  \
        const float q2_ = fmaf(P.H23_2, w3_, P.H22 * w2_);                      \
        const float q3_ = P.H33 * w3_;                                          \
        const float pq_ = fmaf(w0_, q0_, fmaf(w1_, q1_, fmaf(w2_, q2_, w3_ * q3_))); \
        const bool ok_ = !(j == 3 && lane == 63 && !seam);  /* col 511: no patch */ \
        rowsum_ += ok_ ? pq_ : 0.0f;                                            \
    }                                                                           \
    if (valid) acc += (double)rowsum_;                                          \
    TOPF(B, E);                                                                 \
} while (0)

__global__ __launch_bounds__(BSIZE, 4) void helm_main(const float* __restrict__ x,
                                                      float* __restrict__ out,
                                                      HParams P)
{
    const int t    = threadIdx.x;
    const int lane = t & 63;
    const int wid  = t >> 6;
    const int sid  = blockIdx.x * 4 + wid;   // 0..4095 wave-strips
    const int b    = sid >> 8;               // image 0..15
    const int rem  = sid & 255;
    const int half = rem & 1;                // 0: cols 0..255, 1: cols 256..511
    const int rs   = rem >> 1;               // row-strip 0..127
    const int h0   = rs * 4;                 // data rows h0..h0+4
    const bool seam = (half == 0);           // wave-uniform

    const float*  pxf = x + (size_t)b * (4u * 512u * 512u);
    const float4* px  = (const float4*)pxf;
    const int cq = half * 64 + lane;         // lane's float4 index in row

    float4 A0[4], A1[4];
    float  E0[4] = {0.f, 0.f, 0.f, 0.f};
    float  E1[4] = {0.f, 0.f, 0.f, 0.f};
    float  T1[4], T2[4], T4[4];
    float  Tb2 = 0.f, Tb4 = 0.f;
    double acc = 0.0;

    LOADROW(A0, E0, h0);
    LOADROW(A1, E1, h0 + 1);                 // h0+1 <= 509: always valid
    TOPF(A0, E0);

    // k=1: row h0+1 in A1; prefetch h0+2
    LOADROW(A0, E0, h0 + 2);
    ROWSTEP(A1, E1, true);
    // k=2: row h0+2 in A0; prefetch h0+3
    LOADROW(A1, E1, h0 + 3);
    ROWSTEP(A0, E0, true);
    // k=3: row h0+3 in A1; prefetch h0+4 (clamped; only h0=508 clamps)
    LOADROW(A0, E0, min(h0 + 4, 511));
    ROWSTEP(A1, E1, true);
    // k=4: row h0+4 in A0; patch row h0+3 invalid iff h0+3 == 511
    ROWSTEP(A0, E0, (h0 + 3) < 511);

    // ---- block reduction -> one fire-and-forget fp32 atomicAdd ----
    __shared__ double wred[4];
    #pragma unroll
    for (int off = 32; off > 0; off >>= 1)
        acc += __shfl_down(acc, off, 64);
    if (lane == 0) wred[wid] = acc;
    __syncthreads();
    if (t == 0) {
        const double bsum = wred[0] + wred[1] + wred[2] + wred[3];
        atomicAdd(out, (float)(bsum * (1.0 / (16.0 * 511.0 * 511.0))));
    }
}

extern "C" void kernel_launch(void* const* d_in, const int* in_sizes, int n_in,
                              void* d_out, int out_size, void* d_ws, size_t ws_size,
                              hipStream_t stream) {
    const float* x = (const float*)d_in[0];
    float* out     = (float*)d_out;

    // ---- host-side constant computation (double precision) ----
    const double L = 0.01;
    double lm[7];
    lm[0] = L;
    for (int i = 1; i < 7; ++i) lm[i] = lm[i - 1] * L;

    double C1[4][4], C2[4][4] = {}, C3[4][4] = {};
    for (int i = 0; i < 4; ++i)
        for (int j = 0; j < 4; ++j)
            C1[i][j] = lm[i + j] / (double)(i + j + 1);
    C2[2][2] = 4.0 * lm[0];  C2[2][3] = 6.0 * lm[1];
    C2[3][2] = 6.0 * lm[1];  C2[3][3] = 12.0 * lm[2];
    C3[2][0] = 2.0 * lm[0];  C3[2][1] = lm[1];
    C3[2][2] = (2.0 / 3.0) * lm[2];  C3[2][3] = 0.5 * lm[3];
    C3[3][0] = 3.0 * lm[1];  C3[3][1] = 2.0 * lm[2];
    C3[3][2] = 1.5 * lm[3];  C3[3][3] = (6.0 / 5.0) * lm[4];

    const double M[4][4] = {
        {1.0, 0.0, 0.0, 0.0},
        {0.0, 0.0, 1.0, 0.0},
        {-3.0 / lm[1], 3.0 / lm[1], -2.0 / lm[0], -1.0 / lm[0]},
        { 2.0 / lm[2], -2.0 / lm[2], 1.0 / lm[1],  1.0 / lm[1]}
    };

    double s1 = 0.0, s2 = 0.0, s3 = 0.0;
    for (int i = 0; i < 4; ++i)
        for (int j = 0; j < 4; ++j) {
            s1 += C1[i][j]; s2 += C2[i][j]; s3 += C3[i][j];
        }

    const double k2 = 20.0 * 20.0;   // K*K
    const double a1 = s2 + k2 * k2 * s1 + 2.0 * k2 * s3;  // coeff of qC1
    const double a2 = s1;                                 // coeff of qC2
    const double a3 = 2.0 * s3 + 2.0 * k2 * s1;           // coeff of qC3 (+ qC3T == qC3)

    double G[4][4];
    for (int i = 0; i < 4; ++i)
        for (int j = 0; j < 4; ++j)
            G[i][j] = a1 * C1[i][j] + a2 * C2[i][j] + a3 * C3[i][j];

    double H[4][4] = {};
    for (int jj = 0; jj < 4; ++jj)
        for (int kk = 0; kk < 4; ++kk) {
            double s = 0.0;
            for (int a = 0; a < 4; ++a)
                for (int bb = 0; bb < 4; ++bb)
                    s += M[a][jj] * G[a][bb] * M[bb][kk];
            H[jj][kk] = s;
        }
    double Hs[4][4];
    for (int i = 0; i < 4; ++i)
        for (int j = 0; j < 4; ++j)
            Hs[i][j] = 0.5 * (H[i][j] + H[j][i]);

    double u[4];
    for (int j = 0; j < 4; ++j)
        u[j] = M[0][j] + M[1][j] + M[2][j] + M[3][j];

    HParams P;
    P.u0 = (float)u[0]; P.u1 = (float)u[1]; P.u2 = (float)u[2]; P.u3 = (float)u[3];
    P.H00 = (float)Hs[0][0]; P.H11 = (float)Hs[1][1];
    P.H22 = (float)Hs[2][2]; P.H33 = (float)Hs[3][3];
    P.H01_2 = (float)(2.0 * Hs[0][1]); P.H02_2 = (float)(2.0 * Hs[0][2]);
    P.H03_2 = (float)(2.0 * Hs[0][3]); P.H12_2 = (float)(2.0 * Hs[1][2]);
    P.H13_2 = (float)(2.0 * Hs[1][3]); P.H23_2 = (float)(2.0 * Hs[2][3]);

    (void)in_sizes; (void)n_in; (void)out_size; (void)d_ws; (void)ws_size;

    hipMemsetAsync(out, 0, sizeof(float), stream);
    helm_main<<<dim3(NBLK), dim3(BSIZE), 0, stream>>>(x, out, P);
}

// Round 10
// 26.281 us; speedup vs baseline: 1.1967x; 1.1967x over previous
//
#include <hip/hip_runtime.h>

// Helmholtz loss, fully reduced:
//   patch(b,h,w) = w^T H w, w from per-pixel linear fields,
//   H = M^T (a1*C1 + a2*C2 + a3*C3sym) M  (host, double precision).
// Round-10 = round-8 (best: 18.9us) with EXACTLY ONE delta: the separate
// reduce kernel (+graph node gap, ~4-6us) is replaced by one fire-and-
// forget unsafeAtomicAdd (HW global_atomic_add_f32, no CAS, no fence)
// of the pre-scaled block partial into out[0].
//   r9 post-mortem: plain atomicAdd(float) lowers to a CAS loop without
//   -munsafe-fp-atomics -> 1024 contended CAS = +12us. unsafeAtomicAdd
//   emits the hardware fp32 add. r3-r7 pathology (ACQ_REL fetch_add with
//   L2 wb/inv per block) is also absent: relaxed, no return, no fence.
// Hot loop identical to r8: one wave = 4 patch rows x 512 cols, 5 data
// rows streamed with 1-row register lookahead, no LDS/barriers in loop.

struct HParams {
    float u0, u1, u2, u3;
    float H00, H11, H22, H33;
    float H01_2, H02_2, H03_2, H12_2, H13_2, H23_2;
};

#define BSIZE 256
#define NBLK  512

__device__ __forceinline__ float f4get(const float4& v, int k) {
    switch (k & 3) { case 0: return v.x; case 1: return v.y; case 2: return v.z; default: return v.w; }
}

#define LOADROW(B, r) do {                                                      \
    _Pragma("unroll")                                                           \
    for (int ch = 0; ch < 4; ++ch) {                                            \
        const size_t base_ = (size_t)ch * 65536u + (size_t)(r) * 128u + cq;     \
        B[2 * ch]     = px[base_];                                              \
        B[2 * ch + 1] = px[base_ + 1];                                          \
    } } while (0)

#define TOPF(B) do {                                                            \
    _Pragma("unroll")                                                           \
    for (int j = 0; j < 8; ++j) {                                               \
        const float x0_ = f4get(B[0 + (j >> 2)], j);                            \
        const float x1_ = f4get(B[2 + (j >> 2)], j);                            \
        const float x2_ = f4get(B[4 + (j >> 2)], j);                            \
        const float x3_ = f4get(B[6 + (j >> 2)], j);                            \
        const float t0_ = P.u0 * x0_;                                           \
        T1[j] = fmaf(P.u2, x3_, t0_);                                           \
        T2[j] = fmaf(P.u2, x1_, t0_);                                           \
        T4[j] = fmaf(P.u2, x3_, P.u0 * x2_);                                    \
    } } while (0)

__global__ __launch_bounds__(BSIZE, 2) void helm_main(const float* __restrict__ x,
                                                      float* __restrict__ out,
                                                      HParams P)
{
    const int t    = threadIdx.x;
    const int lane = t & 63;
    const int wid  = t >> 6;
    const int sid  = blockIdx.x * 4 + wid;   // 0..2047 wave-strips
    const int b    = sid >> 7;               // image 0..15
    const int rs   = sid & 127;              // row-strip 0..127
    const int h0   = rs * 4;                 // first patch row (data rows h0..h0+4)

    const float4* px = (const float4*)(x + (size_t)b * (4u * 512u * 512u));
    const int cq = lane * 2;                 // lane owns cols [8*lane, 8*lane+8)

    float4 A[2][8];                          // double-buffered data rows
    float  T1[8], T2[8], T4[8];              // top-role fields of current top row
    double acc = 0.0;

    LOADROW(A[0], h0);
    LOADROW(A[1], h0 + 1);                   // h0+1 <= 509: always valid
    TOPF(A[0]);

    #pragma unroll
    for (int k = 1; k <= 4; ++k) {
        const int cur = k & 1;               // row h0+k lives in A[cur]
        const int nxt = cur ^ 1;
        if (k < 4) {
            const int rn = min(h0 + k + 1, 511);   // only h0+4 can need clamping
            LOADROW(A[nxt], rn);
        }
        // bottom-role fields of row h0+k
        float f3[8], f5[8];
        #pragma unroll
        for (int j = 0; j < 8; ++j) {
            const float x0 = f4get(A[cur][0 + (j >> 2)], j);
            const float x1 = f4get(A[cur][2 + (j >> 2)], j);
            const float x2 = f4get(A[cur][4 + (j >> 2)], j);
            const float x3 = f4get(A[cur][6 + (j >> 2)], j);
            f3[j] = fmaf(P.u3, x1, P.u1 * x0);
            f5[j] = fmaf(P.u3, x3, P.u1 * x2);
        }
        // patch w-vectors for patch row h0+k-1
        float aV[8], bV[8], cV[8];
        #pragma unroll
        for (int j = 0; j < 8; ++j) {
            aV[j] = T1[j] + f3[j];
            bV[j] = T2[j] + f3[j];
            cV[j] = T4[j] + f5[j];
        }
        const float bn = __shfl_down(bV[0], 1, 64);
        const float cn = __shfl_down(cV[0], 1, 64);
        float rowsum = 0.0f;
        #pragma unroll
        for (int j = 0; j < 8; ++j) {
            const float w0 = aV[j];
            const float w1 = (j < 7) ? bV[j + 1] : bn;
            const float w2 = cV[j];
            const float w3 = (j < 7) ? cV[j + 1] : cn;
            const float q0 = fmaf(P.H03_2, w3, fmaf(P.H02_2, w2, fmaf(P.H01_2, w1, P.H00 * w0)));
            const float q1 = fmaf(P.H13_2, w3, fmaf(P.H12_2, w2, P.H11 * w1));
            const float q2 = fmaf(P.H23_2, w3, P.H22 * w2);
            const float q3 = P.H33 * w3;
            const float pq = fmaf(w0, q0, fmaf(w1, q1, fmaf(w2, q2, w3 * q3)));
            rowsum += (j < 7 || lane < 63) ? pq : 0.0f;   // col 511: no patch
        }
        if (h0 + k - 1 < 511)                 // wave-uniform validity (row 511: no patch)
            acc += (double)rowsum;
        // adopt row h0+k's top-role fields
        if (k < 4) TOPF(A[cur]);
    }

    // ---- block reduction -> ONE fire-and-forget HW fp32 atomic add ----
    __shared__ double wred[4];
    #pragma unroll
    for (int off = 32; off > 0; off >>= 1)
        acc += __shfl_down(acc, off, 64);
    if (lane == 0) wred[wid] = acc;
    __syncthreads();
    if (t == 0) {
        const double bsum = wred[0] + wred[1] + wred[2] + wred[3];
        unsafeAtomicAdd(out, (float)(bsum * (1.0 / (16.0 * 511.0 * 511.0))));
    }
}

extern "C" void kernel_launch(void* const* d_in, const int* in_sizes, int n_in,
                              void* d_out, int out_size, void* d_ws, size_t ws_size,
                              hipStream_t stream) {
    const float* x = (const float*)d_in[0];
    float* out     = (float*)d_out;

    // ---- host-side constant computation (double precision) ----
    const double L = 0.01;
    double lm[7];
    lm[0] = L;
    for (int i = 1; i < 7; ++i) lm[i] = lm[i - 1] * L;

    double C1[4][4], C2[4][4] = {}, C3[4][4] = {};
    for (int i = 0; i < 4; ++i)
        for (int j = 0; j < 4; ++j)
            C1[i][j] = lm[i + j] / (double)(i + j + 1);
    C2[2][2] = 4.0 * lm[0];  C2[2][3] = 6.0 * lm[1];
    C2[3][2] = 6.0 * lm[1];  C2[3][3] = 12.0 * lm[2];
    C3[2][0] = 2.0 * lm[0];  C3[2][1] = lm[1];
    C3[2][2] = (2.0 / 3.0) * lm[2];  C3[2][3] = 0.5 * lm[3];
    C3[3][0] = 3.0 * lm[1];  C3[3][1] = 2.0 * lm[2];
    C3[3][2] = 1.5 * lm[3];  C3[3][3] = (6.0 / 5.0) * lm[4];

    const double M[4][4] = {
        {1.0, 0.0, 0.0, 0.0},
        {0.0, 0.0, 1.0, 0.0},
        {-3.0 / lm[1], 3.0 / lm[1], -2.0 / lm[0], -1.0 / lm[0]},
        { 2.0 / lm[2], -2.0 / lm[2], 1.0 / lm[1],  1.0 / lm[1]}
    };

    double s1 = 0.0, s2 = 0.0, s3 = 0.0;
    for (int i = 0; i < 4; ++i)
        for (int j = 0; j < 4; ++j) {
            s1 += C1[i][j]; s2 += C2[i][j]; s3 += C3[i][j];
        }

    const double k2 = 20.0 * 20.0;   // K*K
    const double a1 = s2 + k2 * k2 * s1 + 2.0 * k2 * s3;  // coeff of qC1
    const double a2 = s1;                                 // coeff of qC2
    const double a3 = 2.0 * s3 + 2.0 * k2 * s1;           // coeff of qC3 (+ qC3T == qC3)

    double G[4][4];
    for (int i = 0; i < 4; ++i)
        for (int j = 0; j < 4; ++j)
            G[i][j] = a1 * C1[i][j] + a2 * C2[i][j] + a3 * C3[i][j];

    double H[4][4] = {};
    for (int jj = 0; jj < 4; ++jj)
        for (int kk = 0; kk < 4; ++kk) {
            double s = 0.0;
            for (int a = 0; a < 4; ++a)
                for (int bb = 0; bb < 4; ++bb)
                    s += M[a][jj] * G[a][bb] * M[bb][kk];
            H[jj][kk] = s;
        }
    double Hs[4][4];
    for (int i = 0; i < 4; ++i)
        for (int j = 0; j < 4; ++j)
            Hs[i][j] = 0.5 * (H[i][j] + H[j][i]);

    double u[4];
    for (int j = 0; j < 4; ++j)
        u[j] = M[0][j] + M[1][j] + M[2][j] + M[3][j];

    HParams P;
    P.u0 = (float)u[0]; P.u1 = (float)u[1]; P.u2 = (float)u[2]; P.u3 = (float)u[3];
    P.H00 = (float)Hs[0][0]; P.H11 = (float)Hs[1][1];
    P.H22 = (float)Hs[2][2]; P.H33 = (float)Hs[3][3];
    P.H01_2 = (float)(2.0 * Hs[0][1]); P.H02_2 = (float)(2.0 * Hs[0][2]);
    P.H03_2 = (float)(2.0 * Hs[0][3]); P.H12_2 = (float)(2.0 * Hs[1][2]);
    P.H13_2 = (float)(2.0 * Hs[1][3]); P.H23_2 = (float)(2.0 * Hs[2][3]);

    (void)in_sizes; (void)n_in; (void)out_size; (void)d_ws; (void)ws_size;

    hipMemsetAsync(out, 0, sizeof(float), stream);
    helm_main<<<dim3(NBLK), dim3(BSIZE), 0, stream>>>(x, out, P);
}

// Round 11
// 25.933 us; speedup vs baseline: 1.2127x; 1.0134x over previous
//
#include <hip/hip_runtime.h>

// Helmholtz loss, fully reduced:
//   patch(b,h,w) = w^T H w, w from per-pixel linear fields,
//   H = M^T (a1*C1 + a2*C2 + a3*C3sym) M  (host, double precision).
// Round-11 = round-10 with EXACTLY ONE delta: hipMemsetAsync(out,4B) ->
// helm_zero<<<1,1>>> kernel. r10 post-mortem: in-graph fillBufferAligned
// is a heavyweight dispatch (rocprof shows 38-42us even for ~0 bytes);
// the 512 fire-and-forget unsafeAtomicAdds bound at <=14ns each. If this
// lands ~15-17us the fill node was the regression; if ~25 the atomics
// are, and we revert to the r8 two-kernel shell.
// Hot loop identical to r8/r10: one wave = 4 patch rows x 512 cols, 5
// data rows streamed with 1-row register lookahead, no LDS/barriers.

struct HParams {
    float u0, u1, u2, u3;
    float H00, H11, H22, H33;
    float H01_2, H02_2, H03_2, H12_2, H13_2, H23_2;
};

#define BSIZE 256
#define NBLK  512

__device__ __forceinline__ float f4get(const float4& v, int k) {
    switch (k & 3) { case 0: return v.x; case 1: return v.y; case 2: return v.z; default: return v.w; }
}

#define LOADROW(B, r) do {                                                      \
    _Pragma("unroll")                                                           \
    for (int ch = 0; ch < 4; ++ch) {                                            \
        const size_t base_ = (size_t)ch * 65536u + (size_t)(r) * 128u + cq;     \
        B[2 * ch]     = px[base_];                                              \
        B[2 * ch + 1] = px[base_ + 1];                                          \
    } } while (0)

#define TOPF(B) do {                                                            \
    _Pragma("unroll")                                                           \
    for (int j = 0; j < 8; ++j) {                                               \
        const float x0_ = f4get(B[0 + (j >> 2)], j);                            \
        const float x1_ = f4get(B[2 + (j >> 2)], j);                            \
        const float x2_ = f4get(B[4 + (j >> 2)], j);                            \
        const float x3_ = f4get(B[6 + (j >> 2)], j);                            \
        const float t0_ = P.u0 * x0_;                                           \
        T1[j] = fmaf(P.u2, x3_, t0_);                                           \
        T2[j] = fmaf(P.u2, x1_, t0_);                                           \
        T4[j] = fmaf(P.u2, x3_, P.u0 * x2_);                                    \
    } } while (0)

__global__ void helm_zero(float* __restrict__ out) {
    out[0] = 0.0f;
}

__global__ __launch_bounds__(BSIZE, 2) void helm_main(const float* __restrict__ x,
                                                      float* __restrict__ out,
                                                      HParams P)
{
    const int t    = threadIdx.x;
    const int lane = t & 63;
    const int wid  = t >> 6;
    const int sid  = blockIdx.x * 4 + wid;   // 0..2047 wave-strips
    const int b    = sid >> 7;               // image 0..15
    const int rs   = sid & 127;              // row-strip 0..127
    const int h0   = rs * 4;                 // first patch row (data rows h0..h0+4)

    const float4* px = (const float4*)(x + (size_t)b * (4u * 512u * 512u));
    const int cq = lane * 2;                 // lane owns cols [8*lane, 8*lane+8)

    float4 A[2][8];                          // double-buffered data rows
    float  T1[8], T2[8], T4[8];              // top-role fields of current top row
    double acc = 0.0;

    LOADROW(A[0], h0);
    LOADROW(A[1], h0 + 1);                   // h0+1 <= 509: always valid
    TOPF(A[0]);

    #pragma unroll
    for (int k = 1; k <= 4; ++k) {
        const int cur = k & 1;               // row h0+k lives in A[cur]
        const int nxt = cur ^ 1;
        if (k < 4) {
            const int rn = min(h0 + k + 1, 511);   // only h0+4 can need clamping
            LOADROW(A[nxt], rn);
        }
        // bottom-role fields of row h0+k
        float f3[8], f5[8];
        #pragma unroll
        for (int j = 0; j < 8; ++j) {
            const float x0 = f4get(A[cur][0 + (j >> 2)], j);
            const float x1 = f4get(A[cur][2 + (j >> 2)], j);
            const float x2 = f4get(A[cur][4 + (j >> 2)], j);
            const float x3 = f4get(A[cur][6 + (j >> 2)], j);
            f3[j] = fmaf(P.u3, x1, P.u1 * x0);
            f5[j] = fmaf(P.u3, x3, P.u1 * x2);
        }
        // patch w-vectors for patch row h0+k-1
        float aV[8], bV[8], cV[8];
        #pragma unroll
        for (int j = 0; j < 8; ++j) {
            aV[j] = T1[j] + f3[j];
            bV[j] = T2[j] + f3[j];
            cV[j] = T4[j] + f5[j];
        }
        const float bn = __shfl_down(bV[0], 1, 64);
        const float cn = __shfl_down(cV[0], 1, 64);
        float rowsum = 0.0f;
        #pragma unroll
        for (int j = 0; j < 8; ++j) {
            const float w0 = aV[j];
            const float w1 = (j < 7) ? bV[j + 1] : bn;
            const float w2 = cV[j];
            const float w3 = (j < 7) ? cV[j + 1] : cn;
            const float q0 = fmaf(P.H03_2, w3, fmaf(P.H02_2, w2, fmaf(P.H01_2, w1, P.H00 * w0)));
            const float q1 = fmaf(P.H13_2, w3, fmaf(P.H12_2, w2, P.H11 * w1));
            const float q2 = fmaf(P.H23_2, w3, P.H22 * w2);
            const float q3 = P.H33 * w3;
            const float pq = fmaf(w0, q0, fmaf(w1, q1, fmaf(w2, q2, w3 * q3)));
            rowsum += (j < 7 || lane < 63) ? pq : 0.0f;   // col 511: no patch
        }
        if (h0 + k - 1 < 511)                 // wave-uniform validity (row 511: no patch)
            acc += (double)rowsum;
        // adopt row h0+k's top-role fields
        if (k < 4) TOPF(A[cur]);
    }

    // ---- block reduction -> ONE fire-and-forget HW fp32 atomic add ----
    __shared__ double wred[4];
    #pragma unroll
    for (int off = 32; off > 0; off >>= 1)
        acc += __shfl_down(acc, off, 64);
    if (lane == 0) wred[wid] = acc;
    __syncthreads();
    if (t == 0) {
        const double bsum = wred[0] + wred[1] + wred[2] + wred[3];
        unsafeAtomicAdd(out, (float)(bsum * (1.0 / (16.0 * 511.0 * 511.0))));
    }
}

extern "C" void kernel_launch(void* const* d_in, const int* in_sizes, int n_in,
                              void* d_out, int out_size, void* d_ws, size_t ws_size,
                              hipStream_t stream) {
    const float* x = (const float*)d_in[0];
    float* out     = (float*)d_out;

    // ---- host-side constant computation (double precision) ----
    const double L = 0.01;
    double lm[7];
    lm[0] = L;
    for (int i = 1; i < 7; ++i) lm[i] = lm[i - 1] * L;

    double C1[4][4], C2[4][4] = {}, C3[4][4] = {};
    for (int i = 0; i < 4; ++i)
        for (int j = 0; j < 4; ++j)
            C1[i][j] = lm[i + j] / (double)(i + j + 1);
    C2[2][2] = 4.0 * lm[0];  C2[2][3] = 6.0 * lm[1];
    C2[3][2] = 6.0 * lm[1];  C2[3][3] = 12.0 * lm[2];
    C3[2][0] = 2.0 * lm[0];  C3[2][1] = lm[1];
    C3[2][2] = (2.0 / 3.0) * lm[2];  C3[2][3] = 0.5 * lm[3];
    C3[3][0] = 3.0 * lm[1];  C3[3][1] = 2.0 * lm[2];
    C3[3][2] = 1.5 * lm[3];  C3[3][3] = (6.0 / 5.0) * lm[4];

    const double M[4][4] = {
        {1.0, 0.0, 0.0, 0.0},
        {0.0, 0.0, 1.0, 0.0},
        {-3.0 / lm[1], 3.0 / lm[1], -2.0 / lm[0], -1.0 / lm[0]},
        { 2.0 / lm[2], -2.0 / lm[2], 1.0 / lm[1],  1.0 / lm[1]}
    };

    double s1 = 0.0, s2 = 0.0, s3 = 0.0;
    for (int i = 0; i < 4; ++i)
        for (int j = 0; j < 4; ++j) {
            s1 += C1[i][j]; s2 += C2[i][j]; s3 += C3[i][j];
        }

    const double k2 = 20.0 * 20.0;   // K*K
    const double a1 = s2 + k2 * k2 * s1 + 2.0 * k2 * s3;  // coeff of qC1
    const double a2 = s1;                                 // coeff of qC2
    const double a3 = 2.0 * s3 + 2.0 * k2 * s1;           // coeff of qC3 (+ qC3T == qC3)

    double G[4][4];
    for (int i = 0; i < 4; ++i)
        for (int j = 0; j < 4; ++j)
            G[i][j] = a1 * C1[i][j] + a2 * C2[i][j] + a3 * C3[i][j];

    double H[4][4] = {};
    for (int jj = 0; jj < 4; ++jj)
        for (int kk = 0; kk < 4; ++kk) {
            double s = 0.0;
            for (int a = 0; a < 4; ++a)
                for (int bb = 0; bb < 4; ++bb)
                    s += M[a][jj] * G[a][bb] * M[bb][kk];
            H[jj][kk] = s;
        }
    double Hs[4][4];
    for (int i = 0; i < 4; ++i)
        for (int j = 0; j < 4; ++j)
            Hs[i][j] = 0.5 * (H[i][j] + H[j][i]);

    double u[4];
    for (int j = 0; j < 4; ++j)
        u[j] = M[0][j] + M[1][j] + M[2][j] + M[3][j];

    HParams P;
    P.u0 = (float)u[0]; P.u1 = (float)u[1]; P.u2 = (float)u[2]; P.u3 = (float)u[3];
    P.H00 = (float)Hs[0][0]; P.H11 = (float)Hs[1][1];
    P.H22 = (float)Hs[2][2]; P.H33 = (float)Hs[3][3];
    P.H01_2 = (float)(2.0 * Hs[0][1]); P.H02_2 = (float)(2.0 * Hs[0][2]);
    P.H03_2 = (float)(2.0 * Hs[0][3]); P.H12_2 = (float)(2.0 * Hs[1][2]);
    P.H13_2 = (float)(2.0 * Hs[1][3]); P.H23_2 = (float)(2.0 * Hs[2][3]);

    (void)in_sizes; (void)n_in; (void)out_size; (void)d_ws; (void)ws_size;

    helm_zero<<<dim3(1), dim3(1), 0, stream>>>(out);
    helm_main<<<dim3(NBLK), dim3(BSIZE), 0, stream>>>(x, out, P);
}

// Round 12
// 21.336 us; speedup vs baseline: 1.4740x; 1.2154x over previous
//
#include <hip/hip_runtime.h>

// Helmholtz loss, fully reduced:
//   patch(b,h,w) = w^T H w, w from per-pixel linear fields,
//   H = M^T (a1*C1 + a2*C2 + a3*C3sym) M  (host, double precision).
// Round-12 = r9's validated half-width hot loop + r8's atomic-free tail.
//   r10/r11 post-mortem: 512 single-address HW fp32 atomics serialize
//   (~14ns each => +7us). Plain partial stores + tiny reduce kernel is
//   the proven shell (r8, 18.9us). This round's single clean delta vs
//   r8: strips 4 patch rows x 256 cols -> 1024 blocks, 16 waves/CU
//   (2x TLP), seam col 255/256 via wave-uniform broadcast loads.

struct HParams {
    float u0, u1, u2, u3;
    float H00, H11, H22, H33;
    float H01_2, H02_2, H03_2, H12_2, H13_2, H23_2;
};

#define BSIZE 256
#define NBLK  1024

__device__ __forceinline__ float f4get(const float4& v, int k) {
    switch (k & 3) { case 0: return v.x; case 1: return v.y; case 2: return v.z; default: return v.w; }
}

// Load one data row (this wave's 256-col half): 4 ch x 1 float4 per lane,
// plus (half-0 waves only) the col-256 seam scalar per channel, same
// address across all lanes -> single broadcast request.
#define LOADROW(B, E, r) do {                                                   \
    _Pragma("unroll")                                                           \
    for (int ch = 0; ch < 4; ++ch)                                              \
        B[ch] = px[(size_t)ch * 65536u + (size_t)(r) * 128u + (size_t)cq];      \
    if (seam) {                                                                 \
        _Pragma("unroll")                                                       \
        for (int ch = 0; ch < 4; ++ch)                                          \
            E[ch] = pxf[(size_t)ch * 262144u + (size_t)(r) * 512u + 256u];      \
    } } while (0)

// Adopt row in B/E as the "top" row: T1/T2/T4 per col, Tb2/Tb4 at col 256.
#define TOPF(B, E) do {                                                         \
    _Pragma("unroll")                                                           \
    for (int j = 0; j < 4; ++j) {                                               \
        const float x0_ = f4get(B[0], j), x1_ = f4get(B[1], j);                 \
        const float x2_ = f4get(B[2], j), x3_ = f4get(B[3], j);                 \
        const float t0_ = P.u0 * x0_;                                           \
        T1[j] = fmaf(P.u2, x3_, t0_);                                           \
        T2[j] = fmaf(P.u2, x1_, t0_);                                           \
        T4[j] = fmaf(P.u2, x3_, P.u0 * x2_);                                    \
    }                                                                           \
    Tb2 = fmaf(P.u2, E[1], P.u0 * E[0]);                                        \
    Tb4 = fmaf(P.u2, E[3], P.u0 * E[2]);                                        \
} while (0)

// Row in B/E acts as bottom row; accumulate patch row, adopt top fields.
#define ROWSTEP(B, E, valid) do {                                               \
    float f3_[4], f5_[4];                                                       \
    _Pragma("unroll")                                                           \
    for (int j = 0; j < 4; ++j) {                                               \
        const float x0_ = f4get(B[0], j), x1_ = f4get(B[1], j);                 \
        const float x2_ = f4get(B[2], j), x3_ = f4get(B[3], j);                 \
        f3_[j] = fmaf(P.u3, x1_, P.u1 * x0_);                                   \
        f5_[j] = fmaf(P.u3, x3_, P.u1 * x2_);                                   \
    }                                                                           \
    const float Bb3_ = fmaf(P.u3, E[1], P.u1 * E[0]);                           \
    const float Bb5_ = fmaf(P.u3, E[3], P.u1 * E[2]);                           \
    float aV[4], bV[4], cV[4];                                                  \
    _Pragma("unroll")                                                           \
    for (int j = 0; j < 4; ++j) {                                               \
        aV[j] = T1[j] + f3_[j];                                                 \
        bV[j] = T2[j] + f3_[j];                                                 \
        cV[j] = T4[j] + f5_[j];                                                 \
    }                                                                           \
    float bn_ = __shfl_down(bV[0], 1, 64);                                      \
    float cn_ = __shfl_down(cV[0], 1, 64);                                      \
    if (seam && lane == 63) { bn_ = Tb2 + Bb3_; cn_ = Tb4 + Bb5_; }             \
    float rowsum_ = 0.0f;                                                       \
    _Pragma("unroll")                                                           \
    for (int j = 0; j < 4; ++j) {                                               \
        const float w0_ = aV[j];                                                \
        const float w1_ = (j < 3) ? bV[j + 1] : bn_;                            \
        const float w2_ = cV[j];                                                \
        const float w3_ = (j < 3) ? cV[j + 1] : cn_;                            \
        const float q0_ = fmaf(P.H03_2, w3_, fmaf(P.H02_2, w2_, fmaf(P.H01_2, w1_, P.H00 * w0_))); \
        const float q1_ = fmaf(P.H13_2, w3_, fmaf(P.H12_2, w2_, P.H11 * w1_));  \
        const float q2_ = fmaf(P.H23_2, w3_, P.H22 * w2_);                      \
        const float q3_ = P.H33 * w3_;                                          \
        const float pq_ = fmaf(w0_, q0_, fmaf(w1_, q1_, fmaf(w2_, q2_, w3_ * q3_))); \
        const bool ok_ = !(j == 3 && lane == 63 && !seam);  /* col 511: no patch */ \
        rowsum_ += ok_ ? pq_ : 0.0f;                                            \
    }                                                                           \
    if (valid) acc += (double)rowsum_;                                          \
    TOPF(B, E);                                                                 \
} while (0)

__global__ __launch_bounds__(BSIZE, 4) void helm_main(const float* __restrict__ x,
                                                      double* __restrict__ partial,
                                                      HParams P)
{
    const int t    = threadIdx.x;
    const int lane = t & 63;
    const int wid  = t >> 6;
    const int sid  = blockIdx.x * 4 + wid;   // 0..4095 wave-strips
    const int b    = sid >> 8;               // image 0..15
    const int rem  = sid & 255;
    const int half = rem & 1;                // 0: cols 0..255, 1: cols 256..511
    const int rs   = rem >> 1;               // row-strip 0..127
    const int h0   = rs * 4;                 // data rows h0..h0+4
    const bool seam = (half == 0);           // wave-uniform

    const float*  pxf = x + (size_t)b * (4u * 512u * 512u);
    const float4* px  = (const float4*)pxf;
    const int cq = half * 64 + lane;         // lane's float4 index in row

    float4 A0[4], A1[4];
    float  E0[4] = {0.f, 0.f, 0.f, 0.f};
    float  E1[4] = {0.f, 0.f, 0.f, 0.f};
    float  T1[4], T2[4], T4[4];
    float  Tb2 = 0.f, Tb4 = 0.f;
    double acc = 0.0;

    LOADROW(A0, E0, h0);
    LOADROW(A1, E1, h0 + 1);                 // h0+1 <= 509: always valid
    TOPF(A0, E0);

    // k=1: row h0+1 in A1; prefetch h0+2
    LOADROW(A0, E0, h0 + 2);
    ROWSTEP(A1, E1, true);
    // k=2: row h0+2 in A0; prefetch h0+3
    LOADROW(A1, E1, h0 + 3);
    ROWSTEP(A0, E0, true);
    // k=3: row h0+3 in A1; prefetch h0+4 (clamped; only h0=508 clamps)
    LOADROW(A0, E0, min(h0 + 4, 511));
    ROWSTEP(A1, E1, true);
    // k=4: row h0+4 in A0; patch row h0+3 invalid iff h0+3 == 511
    ROWSTEP(A0, E0, (h0 + 3) < 511);

    // ---- block reduction, plain store of the partial (no atomics) ----
    __shared__ double wred[4];
    #pragma unroll
    for (int off = 32; off > 0; off >>= 1)
        acc += __shfl_down(acc, off, 64);
    if (lane == 0) wred[wid] = acc;
    __syncthreads();
    if (t == 0)
        partial[blockIdx.x] = wred[0] + wred[1] + wred[2] + wred[3];
}

__global__ __launch_bounds__(BSIZE) void helm_reduce(const double* __restrict__ partial,
                                                     float* __restrict__ out, int n)
{
    __shared__ double wsum[4];
    const int t = threadIdx.x;
    double a = 0.0;
    for (int i = t; i < n; i += BSIZE) a += partial[i];
    #pragma unroll
    for (int off = 32; off > 0; off >>= 1)
        a += __shfl_down(a, off, 64);
    if ((t & 63) == 0) wsum[t >> 6] = a;
    __syncthreads();
    if (t == 0) {
        const double sum = wsum[0] + wsum[1] + wsum[2] + wsum[3];
        out[0] = (float)(sum / (16.0 * 511.0 * 511.0));
    }
}

extern "C" void kernel_launch(void* const* d_in, const int* in_sizes, int n_in,
                              void* d_out, int out_size, void* d_ws, size_t ws_size,
                              hipStream_t stream) {
    const float* x  = (const float*)d_in[0];
    float* out      = (float*)d_out;
    double* partial = (double*)d_ws;     // NBLK doubles = 8 KB

    // ---- host-side constant computation (double precision) ----
    const double L = 0.01;
    double lm[7];
    lm[0] = L;
    for (int i = 1; i < 7; ++i) lm[i] = lm[i - 1] * L;

    double C1[4][4], C2[4][4] = {}, C3[4][4] = {};
    for (int i = 0; i < 4; ++i)
        for (int j = 0; j < 4; ++j)
            C1[i][j] = lm[i + j] / (double)(i + j + 1);
    C2[2][2] = 4.0 * lm[0];  C2[2][3] = 6.0 * lm[1];
    C2[3][2] = 6.0 * lm[1];  C2[3][3] = 12.0 * lm[2];
    C3[2][0] = 2.0 * lm[0];  C3[2][1] = lm[1];
    C3[2][2] = (2.0 / 3.0) * lm[2];  C3[2][3] = 0.5 * lm[3];
    C3[3][0] = 3.0 * lm[1];  C3[3][1] = 2.0 * lm[2];
    C3[3][2] = 1.5 * lm[3];  C3[3][3] = (6.0 / 5.0) * lm[4];

    const double M[4][4] = {
        {1.0, 0.0, 0.0, 0.0},
        {0.0, 0.0, 1.0, 0.0},
        {-3.0 / lm[1], 3.0 / lm[1], -2.0 / lm[0], -1.0 / lm[0]},
        { 2.0 / lm[2], -2.0 / lm[2], 1.0 / lm[1],  1.0 / lm[1]}
    };

    double s1 = 0.0, s2 = 0.0, s3 = 0.0;
    for (int i = 0; i < 4; ++i)
        for (int j = 0; j < 4; ++j) {
            s1 += C1[i][j]; s2 += C2[i][j]; s3 += C3[i][j];
        }

    const double k2 = 20.0 * 20.0;   // K*K
    const double a1 = s2 + k2 * k2 * s1 + 2.0 * k2 * s3;  // coeff of qC1
    const double a2 = s1;                                 // coeff of qC2
    const double a3 = 2.0 * s3 + 2.0 * k2 * s1;           // coeff of qC3 (+ qC3T == qC3)

    double G[4][4];
    for (int i = 0; i < 4; ++i)
        for (int j = 0; j < 4; ++j)
            G[i][j] = a1 * C1[i][j] + a2 * C2[i][j] + a3 * C3[i][j];

    double H[4][4] = {};
    for (int jj = 0; jj < 4; ++jj)
        for (int kk = 0; kk < 4; ++kk) {
            double s = 0.0;
            for (int a = 0; a < 4; ++a)
                for (int bb = 0; bb < 4; ++bb)
                    s += M[a][jj] * G[a][bb] * M[bb][kk];
            H[jj][kk] = s;
        }
    double Hs[4][4];
    for (int i = 0; i < 4; ++i)
        for (int j = 0; j < 4; ++j)
            Hs[i][j] = 0.5 * (H[i][j] + H[j][i]);

    double u[4];
    for (int j = 0; j < 4; ++j)
        u[j] = M[0][j] + M[1][j] + M[2][j] + M[3][j];

    HParams P;
    P.u0 = (float)u[0]; P.u1 = (float)u[1]; P.u2 = (float)u[2]; P.u3 = (float)u[3];
    P.H00 = (float)Hs[0][0]; P.H11 = (float)Hs[1][1];
    P.H22 = (float)Hs[2][2]; P.H33 = (float)Hs[3][3];
    P.H01_2 = (float)(2.0 * Hs[0][1]); P.H02_2 = (float)(2.0 * Hs[0][2]);
    P.H03_2 = (float)(2.0 * Hs[0][3]); P.H12_2 = (float)(2.0 * Hs[1][2]);
    P.H13_2 = (float)(2.0 * Hs[1][3]); P.H23_2 = (float)(2.0 * Hs[2][3]);

    (void)in_sizes; (void)n_in; (void)out_size; (void)ws_size;

    helm_main<<<dim3(NBLK), dim3(BSIZE), 0, stream>>>(x, partial, P);
    helm_reduce<<<dim3(1), dim3(BSIZE), 0, stream>>>(partial, out, NBLK);
}

// Round 13
// 18.981 us; speedup vs baseline: 1.6569x; 1.1241x over previous
//
#include <hip/hip_runtime.h>

// Helmholtz loss, fully reduced:
//   patch(b,h,w) = w^T H w, w from per-pixel linear fields,
//   H = M^T (a1*C1 + a2*C2 + a3*C3sym) M  (host, double precision).
// Round-13 = EXACT round-8 (measured optimum, 18.9us). All deviations
// tested r9-r12 regressed: LDS staging (+61), ACQ_REL atomic (+68),
// single-address HW fp32 atomic tail (+7), half-width strips (+2.4).
// Main kernel is within ~8% of its 80MB traffic floor (12.7us at the
// ~6.5-6.8 TB/s this part sustains); remainder is fixed 2-dispatch
// overhead. One wave = 4 patch rows x 512 cols; 5 data rows streamed
// with 1-row register lookahead; no LDS/no barriers in hot loop; plain
// partial stores + tiny reduce kernel (atomic-free tail).

struct HParams {
    float u0, u1, u2, u3;
    float H00, H11, H22, H33;
    float H01_2, H02_2, H03_2, H12_2, H13_2, H23_2;
};

#define BSIZE 256
#define NBLK  512

__device__ __forceinline__ float f4get(const float4& v, int k) {
    switch (k & 3) { case 0: return v.x; case 1: return v.y; case 2: return v.z; default: return v.w; }
}

#define LOADROW(B, r) do {                                                      \
    _Pragma("unroll")                                                           \
    for (int ch = 0; ch < 4; ++ch) {                                            \
        const size_t base_ = (size_t)ch * 65536u + (size_t)(r) * 128u + cq;     \
        B[2 * ch]     = px[base_];                                              \
        B[2 * ch + 1] = px[base_ + 1];                                          \
    } } while (0)

#define TOPF(B) do {                                                            \
    _Pragma("unroll")                                                           \
    for (int j = 0; j < 8; ++j) {                                               \
        const float x0_ = f4get(B[0 + (j >> 2)], j);                            \
        const float x1_ = f4get(B[2 + (j >> 2)], j);                            \
        const float x2_ = f4get(B[4 + (j >> 2)], j);                            \
        const float x3_ = f4get(B[6 + (j >> 2)], j);                            \
        const float t0_ = P.u0 * x0_;                                           \
        T1[j] = fmaf(P.u2, x3_, t0_);                                           \
        T2[j] = fmaf(P.u2, x1_, t0_);                                           \
        T4[j] = fmaf(P.u2, x3_, P.u0 * x2_);                                    \
    } } while (0)

__global__ __launch_bounds__(BSIZE, 2) void helm_main(const float* __restrict__ x,
                                                      double* __restrict__ partial,
                                                      HParams P)
{
    const int t    = threadIdx.x;
    const int lane = t & 63;
    const int wid  = t >> 6;
    const int sid  = blockIdx.x * 4 + wid;   // 0..2047 wave-strips
    const int b    = sid >> 7;               // image 0..15
    const int rs   = sid & 127;              // row-strip 0..127
    const int h0   = rs * 4;                 // first patch row (data rows h0..h0+4)

    const float4* px = (const float4*)(x + (size_t)b * (4u * 512u * 512u));
    const int cq = lane * 2;                 // lane owns cols [8*lane, 8*lane+8)

    float4 A[2][8];                          // double-buffered data rows
    float  T1[8], T2[8], T4[8];              // top-role fields of current top row
    double acc = 0.0;

    LOADROW(A[0], h0);
    LOADROW(A[1], h0 + 1);                   // h0+1 <= 509: always valid
    TOPF(A[0]);

    #pragma unroll
    for (int k = 1; k <= 4; ++k) {
        const int cur = k & 1;               // row h0+k lives in A[cur]
        const int nxt = cur ^ 1;
        if (k < 4) {
            const int rn = min(h0 + k + 1, 511);   // only h0+4 can need clamping
            LOADROW(A[nxt], rn);
        }
        // bottom-role fields of row h0+k
        float f3[8], f5[8];
        #pragma unroll
        for (int j = 0; j < 8; ++j) {
            const float x0 = f4get(A[cur][0 + (j >> 2)], j);
            const float x1 = f4get(A[cur][2 + (j >> 2)], j);
            const float x2 = f4get(A[cur][4 + (j >> 2)], j);
            const float x3 = f4get(A[cur][6 + (j >> 2)], j);
            f3[j] = fmaf(P.u3, x1, P.u1 * x0);
            f5[j] = fmaf(P.u3, x3, P.u1 * x2);
        }
        // patch w-vectors for patch row h0+k-1
        float aV[8], bV[8], cV[8];
        #pragma unroll
        for (int j = 0; j < 8; ++j) {
            aV[j] = T1[j] + f3[j];
            bV[j] = T2[j] + f3[j];
            cV[j] = T4[j] + f5[j];
        }
        const float bn = __shfl_down(bV[0], 1, 64);
        const float cn = __shfl_down(cV[0], 1, 64);
        float rowsum = 0.0f;
        #pragma unroll
        for (int j = 0; j < 8; ++j) {
            const float w0 = aV[j];
            const float w1 = (j < 7) ? bV[j + 1] : bn;
            const float w2 = cV[j];
            const float w3 = (j < 7) ? cV[j + 1] : cn;
            const float q0 = fmaf(P.H03_2, w3, fmaf(P.H02_2, w2, fmaf(P.H01_2, w1, P.H00 * w0)));
            const float q1 = fmaf(P.H13_2, w3, fmaf(P.H12_2, w2, P.H11 * w1));
            const float q2 = fmaf(P.H23_2, w3, P.H22 * w2);
            const float q3 = P.H33 * w3;
            const float pq = fmaf(w0, q0, fmaf(w1, q1, fmaf(w2, q2, w3 * q3)));
            rowsum += (j < 7 || lane < 63) ? pq : 0.0f;   // col 511: no patch
        }
        if (h0 + k - 1 < 511)                 // wave-uniform validity (row 511: no patch)
            acc += (double)rowsum;
        // adopt row h0+k's top-role fields
        if (k < 4) TOPF(A[cur]);
    }

    // ---- block reduction, plain store of the partial (no atomics) ----
    __shared__ double wred[4];
    #pragma unroll
    for (int off = 32; off > 0; off >>= 1)
        acc += __shfl_down(acc, off, 64);
    if (lane == 0) wred[wid] = acc;
    __syncthreads();
    if (t == 0)
        partial[blockIdx.x] = wred[0] + wred[1] + wred[2] + wred[3];
}

__global__ __launch_bounds__(BSIZE) void helm_reduce(const double* __restrict__ partial,
                                                     float* __restrict__ out, int n)
{
    __shared__ double wsum[4];
    const int t = threadIdx.x;
    double a = 0.0;
    for (int i = t; i < n; i += BSIZE) a += partial[i];
    #pragma unroll
    for (int off = 32; off > 0; off >>= 1)
        a += __shfl_down(a, off, 64);
    if ((t & 63) == 0) wsum[t >> 6] = a;
    __syncthreads();
    if (t == 0) {
        const double sum = wsum[0] + wsum[1] + wsum[2] + wsum[3];
        out[0] = (float)(sum / (16.0 * 511.0 * 511.0));
    }
}

extern "C" void kernel_launch(void* const* d_in, const int* in_sizes, int n_in,
                              void* d_out, int out_size, void* d_ws, size_t ws_size,
                              hipStream_t stream) {
    const float* x  = (const float*)d_in[0];
    float* out      = (float*)d_out;
    double* partial = (double*)d_ws;     // NBLK doubles = 4 KB

    // ---- host-side constant computation (double precision) ----
    const double L = 0.01;
    double lm[7];
    lm[0] = L;
    for (int i = 1; i < 7; ++i) lm[i] = lm[i - 1] * L;

    double C1[4][4], C2[4][4] = {}, C3[4][4] = {};
    for (int i = 0; i < 4; ++i)
        for (int j = 0; j < 4; ++j)
            C1[i][j] = lm[i + j] / (double)(i + j + 1);
    C2[2][2] = 4.0 * lm[0];  C2[2][3] = 6.0 * lm[1];
    C2[3][2] = 6.0 * lm[1];  C2[3][3] = 12.0 * lm[2];
    C3[2][0] = 2.0 * lm[0];  C3[2][1] = lm[1];
    C3[2][2] = (2.0 / 3.0) * lm[2];  C3[2][3] = 0.5 * lm[3];
    C3[3][0] = 3.0 * lm[1];  C3[3][1] = 2.0 * lm[2];
    C3[3][2] = 1.5 * lm[3];  C3[3][3] = (6.0 / 5.0) * lm[4];

    const double M[4][4] = {
        {1.0, 0.0, 0.0, 0.0},
        {0.0, 0.0, 1.0, 0.0},
        {-3.0 / lm[1], 3.0 / lm[1], -2.0 / lm[0], -1.0 / lm[0]},
        { 2.0 / lm[2], -2.0 / lm[2], 1.0 / lm[1],  1.0 / lm[1]}
    };

    double s1 = 0.0, s2 = 0.0, s3 = 0.0;
    for (int i = 0; i < 4; ++i)
        for (int j = 0; j < 4; ++j) {
            s1 += C1[i][j]; s2 += C2[i][j]; s3 += C3[i][j];
        }

    const double k2 = 20.0 * 20.0;   // K*K
    const double a1 = s2 + k2 * k2 * s1 + 2.0 * k2 * s3;  // coeff of qC1
    const double a2 = s1;                                 // coeff of qC2
    const double a3 = 2.0 * s3 + 2.0 * k2 * s1;           // coeff of qC3 (+ qC3T == qC3)

    double G[4][4];
    for (int i = 0; i < 4; ++i)
        for (int j = 0; j < 4; ++j)
            G[i][j] = a1 * C1[i][j] + a2 * C2[i][j] + a3 * C3[i][j];

    double H[4][4] = {};
    for (int jj = 0; jj < 4; ++jj)
        for (int kk = 0; kk < 4; ++kk) {
            double s = 0.0;
            for (int a = 0; a < 4; ++a)
                for (int bb = 0; bb < 4; ++bb)
                    s += M[a][jj] * G[a][bb] * M[bb][kk];
            H[jj][kk] = s;
        }
    double Hs[4][4];
    for (int i = 0; i < 4; ++i)
        for (int j = 0; j < 4; ++j)
            Hs[i][j] = 0.5 * (H[i][j] + H[j][i]);

    double u[4];
    for (int j = 0; j < 4; ++j)
        u[j] = M[0][j] + M[1][j] + M[2][j] + M[3][j];

    HParams P;
    P.u0 = (float)u[0]; P.u1 = (float)u[1]; P.u2 = (float)u[2]; P.u3 = (float)u[3];
    P.H00 = (float)Hs[0][0]; P.H11 = (float)Hs[1][1];
    P.H22 = (float)Hs[2][2]; P.H33 = (float)Hs[3][3];
    P.H01_2 = (float)(2.0 * Hs[0][1]); P.H02_2 = (float)(2.0 * Hs[0][2]);
    P.H03_2 = (float)(2.0 * Hs[0][3]); P.H12_2 = (float)(2.0 * Hs[1][2]);
    P.H13_2 = (float)(2.0 * Hs[1][3]); P.H23_2 = (float)(2.0 * Hs[2][3]);

    (void)in_sizes; (void)n_in; (void)out_size; (void)ws_size;

    helm_main<<<dim3(NBLK), dim3(BSIZE), 0, stream>>>(x, partial, P);
    helm_reduce<<<dim3(1), dim3(BSIZE), 0, stream>>>(partial, out, NBLK);
}